// Round 8
// baseline (188.345 us; speedup 1.0000x reference)
//
#include <hip/hip_runtime.h>
#include <hip/hip_bf16.h>
#include <hip/hip_fp16.h>

// GeneratorSDF: latent-conditioned MLP SDF on a 128^3 grid (fp32 I/O).
// dims: 67 -> 128 -> 64 -> 32 -> 1 (relu, relu, relu, sigmoid)
//
// R30 = R29's depth-2 pipeline, SCRATCH-SAFE. R29 post-mortem: the deferred
// accumulators were C arrays passed into lambdas (pointer decay -> address-
// taken -> allocated in SCRATCH, rule #20): WRITE_SIZE 8.2MB->172MB of spill
// traffic at only 128 VGPR. The depth-2 hypothesis was VOID, not refuted;
// the schedule itself verified correct (test passed). R30 keeps the exact
// R29 schedule but holds cross-iteration state in a struct of NAMED f32x4
// members (Acc8) -- no indexing, no address-taking, SROA-friendly. aphase2
// also issues its 32 MFMAs kb-outer (8 interleaved chains vs 2). Estimated
// ~152 arch VGPR + 80 AGPR = 232 < 256 budget at 2 waves/SIMD.
// Schedule (pipeline idx i, groups g=2i,2i+1): compute@i (E->Aa, O->Ab),
// pack+write@i+1 (E packs Ab->slots 2,3; O packs Aa->slots 0,1),
// prefetch+bphase@i+2 (E reads 0,1; O reads 2,3). cphase deferred one
// half-body, placed before the zf overwrite. 4 h2 slots, no overlap.
// Ledger: R22 53.5 | R23 57.1 | R24 58.7 | R25 134(spill) | R26 54.1 |
// R27 52.0 | R28 50.0 (best) | R29 void(scratch). Pre-commit: clean-fit
// null => R28-class structure is the practical ceiling; spill signature
// (FETCH >> 400KB) => revert R28 and declare.
// MFMA layouts (verified m89/m91): A[m=lane&15][k=quad*8+j],
// B[k=quad*8+j][n=lane&15], C/D row=quad*4+reg, col=lane&15.

#define NPTS (128 * 128 * 128)

typedef float f32x4_t __attribute__((ext_vector_type(4)));
typedef float f32x2_t __attribute__((ext_vector_type(2)));
typedef __fp16 g16x2_t __attribute__((ext_vector_type(2)));    // VALU half2 (cvt_pkrtz type)
typedef _Float16 h16x8_t __attribute__((ext_vector_type(8)));  // MFMA fragment

__device__ __forceinline__ unsigned h2u(g16x2_t h) {
    unsigned u;
    __builtin_memcpy(&u, &h, 4);
    return u;
}
__device__ __forceinline__ g16x2_t u2h(unsigned u) {
    g16x2_t h;
    __builtin_memcpy(&h, &u, 4);
    return h;
}

// Cross-iteration accumulator state: NAMED members only (never indexed,
// never address-taken at ABI level -- lambdas inline, SROA scalarizes).
struct Acc8 {
    f32x4_t x0, x1, x2, x3;   // rail X, mt 0..3
    f32x4_t y0, y1, y2, y3;   // rail Y, mt 0..3
};

__global__ __launch_bounds__(256, 2) void mlp_kernel(
    const float* __restrict__ x,  const float* __restrict__ W1,
    const float* __restrict__ b1, const float* __restrict__ W2,
    const float* __restrict__ b2, const float* __restrict__ W3,
    const float* __restrict__ b3, const float* __restrict__ W4,
    const float* __restrict__ b4, float* __restrict__ out) {
    __shared__ __align__(16) unsigned s_basep[32][64];  // half2 {base[2c],base[2c+1]} per j
    __shared__ __align__(16) unsigned s_wcp[64];        // half2 wc pairs
    __shared__ __align__(16) float s_b2[64];
    __shared__ __align__(16) float s_b3[32];
    __shared__ __align__(16) float s_w4[32];
    // Union (45 KB): staging = w2a[16][64][8] halves (0..8191) + w3a[4][64][8]
    // (8192..10239) + W1-fold partials (floats at shorts 10240..11263, transient);
    // runtime = h2 slots [w][4][16][72] shorts (0..18431) + zf floats
    // (shorts 18432..22527 = float[4][8][16][4] : w*512 + zi*64 + i*4 + q).
    __shared__ __align__(16) unsigned short s_u[22528];

    const int t = threadIdx.x;
    const int w = t >> 6;
    const int lane = t & 63;
    const int quad = lane >> 4;
    const int l15 = lane & 15;
    const float step = 2.0f / 127.0f;

    // ================= per-block prep, phase 1 (all 256 threads) =============
    // W1 fold partials: thread covers channel-pair p = t&63, c in [h*16,(h+1)*16)
    {
        const int p = t & 63, h = t >> 6;
        const float* r0 = W1 + (2 * p) * 67 + h * 16;
        const float* r1 = r0 + 67;
        const float* xh = x + h * 16;
        float s0 = 0.0f, s1 = 0.0f;
#pragma unroll
        for (int c = 0; c < 16; ++c) {
            const float xc = xh[c];
            s0 = fmaf(r0[c], xc, s0);
            s1 = fmaf(r1[c], xc, s1);
        }
        float2* psum = (float2*)&s_u[10240];   // [h][p], 4 x 64 float2
        psum[h * 64 + p] = make_float2(s0, s1);
    }
    // W2 [64][128] -> f16 A-frag staging (pairs along k)
    const float2* W2v = (const float2*)W2;
#pragma unroll
    for (int it = 0; it < 16; ++it) {
        int pidx = t + 256 * it;
        int idx2 = pidx * 2;
        int o = idx2 >> 7, k = idx2 & 127;
        int mt = o >> 4, lm = o & 15;
        int kb = k >> 5, q = (k >> 3) & 3, jj = k & 7;
        float2 v = W2v[pidx];
        *(unsigned*)&s_u[(mt * 4 + kb) * 512 + (q * 16 + lm) * 8 + jj] =
            h2u(__builtin_amdgcn_cvt_pkrtz(v.x, v.y));
    }
    // W3 [32][64] -> f16 A-frag staging
    const float2* W3v = (const float2*)W3;
#pragma unroll
    for (int it = 0; it < 4; ++it) {
        int pidx = t + 256 * it;
        int idx2 = pidx * 2;
        int o = idx2 >> 6, k = idx2 & 63;
        int mt = o >> 4, lm = o & 15;
        int kb = k >> 5, q = (k >> 3) & 3, jj = k & 7;
        float2 v = W3v[pidx];
        *(unsigned*)&s_u[8192 + (mt * 2 + kb) * 512 + (q * 16 + lm) * 8 + jj] =
            h2u(__builtin_amdgcn_cvt_pkrtz(v.x, v.y));
    }
    if (t < 64) s_b2[t] = b2[t];
    if (t < 32) {
        s_b3[t] = b3[t];
        s_w4[t] = W4[t];
    }
    const float bias4 = b4[0];
    __syncthreads();

    // ================= prep phase 2 (t<64): combine partials + pack tables ====
    // Block covers gi = bid>>2 (a-coord), gj0 = (bid&3)*32 (32 j-rows), all k.
    if (t < 64) {
        const float2* psum = (const float2*)&s_u[10240];
        float2 q0 = psum[t], q1 = psum[64 + t], q2 = psum[128 + t], q3 = psum[192 + t];
        float s0 = b1[2 * t] + (q0.x + q1.x) + (q2.x + q3.x);
        float s1 = b1[2 * t + 1] + (q0.y + q1.y) + (q2.y + q3.y);
        const float* r0 = W1 + (2 * t) * 67;
        const float* r1 = r0 + 67;
        const float pa = -1.0f + step * (float)(blockIdx.x >> 2);   // gi
        const float base0 = fmaf(r0[64], pa, s0);
        const float base1 = fmaf(r1[64], pa, s1);
        const float wb0 = r0[65], wb1 = r1[65];
        const int gj0 = (blockIdx.x & 3) * 32;
        s_wcp[t] = h2u(__builtin_amdgcn_cvt_pkrtz(r0[66], r1[66]));
#pragma unroll
        for (int j = 0; j < 32; ++j) {
            const float pb = -1.0f + step * (float)(gj0 + j);
            s_basep[j][t] = h2u(__builtin_amdgcn_cvt_pkrtz(
                fmaf(wb0, pb, base0), fmaf(wb1, pb, base1)));
        }
    }
    __syncthreads();

    // ================= per-wave fragment preload =================
    h16x8_t a2[16];
#pragma unroll
    for (int f = 0; f < 16; ++f) a2[f] = *(const h16x8_t*)&s_u[f * 512 + lane * 8];
    h16x8_t a3[4];
#pragma unroll
    for (int f = 0; f < 4; ++f) a3[f] = *(const h16x8_t*)&s_u[8192 + f * 512 + lane * 8];
    f32x4_t b2q[4];
#pragma unroll
    for (int mt = 0; mt < 4; ++mt) b2q[mt] = *(const f32x4_t*)&s_b2[mt * 16 + quad * 4];
    f32x4_t b3q[2];
    f32x2_t w4lo[2], w4hi[2];
#pragma unroll
    for (int mt = 0; mt < 2; ++mt) {
        b3q[mt] = *(const f32x4_t*)&s_b3[mt * 16 + quad * 4];
        float4 wq = *(const float4*)&s_w4[mt * 16 + quad * 4];
        w4lo[mt][0] = wq.x; w4lo[mt][1] = wq.y;
        w4hi[mt][0] = wq.z; w4hi[mt][1] = wq.w;
    }
    // wc pairs: loop-invariant, 16 packed regs, pinned
    unsigned twp[16];
#pragma unroll
    for (int kb = 0; kb < 4; ++kb) {
        uint4 v = *(const uint4*)&s_wcp[kb * 16 + quad * 4];
        twp[kb * 4 + 0] = v.x; twp[kb * 4 + 1] = v.y;
        twp[kb * 4 + 2] = v.z; twp[kb * 4 + 3] = v.w;
    }
#pragma unroll
    for (int i = 0; i < 16; ++i) asm volatile("" : "+v"(twp[i]));
    __syncthreads();  // union handoff: staging -> h2/zf scratch

    const int sw = (l15 & 1) * 32;                    // h2 channel swizzle (shorts)
    unsigned short* h2w = &s_u[w * 4608];             // 4 slots x 16 pts x 72 shorts
    unsigned short* h2p = h2w + l15 * 72;             // per-lane point base
    float* zf = (float*)&s_u[18432];                  // [w][zi][i][q]
    const f32x2_t zero2 = {0.0f, 0.0f};
    const g16x2_t zero2h = {(__fp16)0.0f, (__fp16)0.0f};
    const int outbase = blockIdx.x * 4096 + w * 1024;

    // ---- phase bodies (slot/zf indices are call-site constants) ----
    unsigned tbp[16];
    // A-phase x2: layer 1 + layer 2 for local groups pgl, pgl+1 -> Acc8.
    // MFMAs issued kb-outer: 8 independent accumulation chains interleaved.
    auto aphase2 = [&](int pgl, Acc8& A) {
        const float pcX = fmaf(step, (float)((pgl * 16) + l15), -1.0f);
        const float pcY = fmaf(step, (float)(((pgl + 1) * 16) + l15), -1.0f);
        const g16x2_t pc2X = __builtin_amdgcn_cvt_pkrtz(pcX, pcX);
        const g16x2_t pc2Y = __builtin_amdgcn_cvt_pkrtz(pcY, pcY);
        h16x8_t bfX[4], bfY[4];
#pragma unroll
        for (int kb = 0; kb < 4; ++kb) {
            union { h16x8_t v; g16x2_t h[4]; } bx, by;
#pragma unroll
            for (int p = 0; p < 4; ++p) {
                g16x2_t tw = u2h(twp[kb * 4 + p]);
                g16x2_t tb = u2h(tbp[kb * 4 + p]);
                g16x2_t hx = __builtin_elementwise_fma(tw, pc2X, tb);
                g16x2_t hy = __builtin_elementwise_fma(tw, pc2Y, tb);
                bx.h[p] = __builtin_elementwise_max(hx, zero2h);
                by.h[p] = __builtin_elementwise_max(hy, zero2h);
            }
            bfX[kb] = bx.v;
            bfY[kb] = by.v;
        }
        f32x4_t cX0 = b2q[0], cY0 = b2q[0], cX1 = b2q[1], cY1 = b2q[1];
        f32x4_t cX2 = b2q[2], cY2 = b2q[2], cX3 = b2q[3], cY3 = b2q[3];
#pragma unroll
        for (int kb = 0; kb < 4; ++kb) {
            cX0 = __builtin_amdgcn_mfma_f32_16x16x32_f16(a2[0 + kb],  bfX[kb], cX0, 0, 0, 0);
            cY0 = __builtin_amdgcn_mfma_f32_16x16x32_f16(a2[0 + kb],  bfY[kb], cY0, 0, 0, 0);
            cX1 = __builtin_amdgcn_mfma_f32_16x16x32_f16(a2[4 + kb],  bfX[kb], cX1, 0, 0, 0);
            cY1 = __builtin_amdgcn_mfma_f32_16x16x32_f16(a2[4 + kb],  bfY[kb], cY1, 0, 0, 0);
            cX2 = __builtin_amdgcn_mfma_f32_16x16x32_f16(a2[8 + kb],  bfX[kb], cX2, 0, 0, 0);
            cY2 = __builtin_amdgcn_mfma_f32_16x16x32_f16(a2[8 + kb],  bfY[kb], cY2, 0, 0, 0);
            cX3 = __builtin_amdgcn_mfma_f32_16x16x32_f16(a2[12 + kb], bfX[kb], cX3, 0, 0, 0);
            cY3 = __builtin_amdgcn_mfma_f32_16x16x32_f16(a2[12 + kb], bfY[kb], cY3, 0, 0, 0);
        }
        A.x0 = cX0; A.x1 = cX1; A.x2 = cX2; A.x3 = cX3;
        A.y0 = cY0; A.y1 = cY1; A.y2 = cY2; A.y3 = cY3;
    };
    // pack one mt-slice of both rails + write to slots (off is constant)
    auto pk1 = [&](const f32x4_t& ax, const f32x4_t& ay, int off,
                   unsigned short* slotX, unsigned short* slotY) {
        g16x2_t loX = __builtin_elementwise_max(
            __builtin_amdgcn_cvt_pkrtz(ax[0], ax[1]), zero2h);
        g16x2_t loY = __builtin_elementwise_max(
            __builtin_amdgcn_cvt_pkrtz(ay[0], ay[1]), zero2h);
        g16x2_t hiX = __builtin_elementwise_max(
            __builtin_amdgcn_cvt_pkrtz(ax[2], ax[3]), zero2h);
        g16x2_t hiY = __builtin_elementwise_max(
            __builtin_amdgcn_cvt_pkrtz(ay[2], ay[3]), zero2h);
        uint2 pkX, pkY;
        pkX.x = h2u(loX); pkX.y = h2u(hiX);
        pkY.x = h2u(loY); pkY.y = h2u(hiY);
        *(uint2*)&slotX[(off + quad * 4) ^ sw] = pkX;
        *(uint2*)&slotY[(off + quad * 4) ^ sw] = pkY;
    };
    // pack + relu + h2 writes for a rail pair into slots s0, s1 (constants)
    auto packstore2 = [&](int s0, int s1, const Acc8& A) {
        unsigned short* slotX = h2p + s0 * 1152;
        unsigned short* slotY = h2p + s1 * 1152;
        pk1(A.x0, A.y0, 0,  slotX, slotY);
        pk1(A.x1, A.y1, 16, slotX, slotY);
        pk1(A.x2, A.y2, 32, slotX, slotY);
        pk1(A.x3, A.y3, 48, slotX, slotY);
    };
    // prefetch b3 B-fragments from slots s0, s1 (constants)
    auto prefetch2 = [&](int s0, int s1, h16x8_t& f0, h16x8_t& f1,
                         h16x8_t& f2, h16x8_t& f3) {
        const unsigned short* ps0 = h2p + s0 * 1152;
        const unsigned short* ps1 = h2p + s1 * 1152;
        f0 = *(const h16x8_t*)&ps0[(0 ^ sw) + quad * 8];
        f1 = *(const h16x8_t*)&ps0[(32 ^ sw) + quad * 8];
        f2 = *(const h16x8_t*)&ps1[(0 ^ sw) + quad * 8];
        f3 = *(const h16x8_t*)&ps1[(32 ^ sw) + quad * 8];
    };
    // B-phase x2: layer 3 + w4-dot; zf indices zi0, zi1 (constants)
    auto bphase2 = [&](int zi0, int zi1, h16x8_t af0, h16x8_t af1,
                       h16x8_t bf0, h16x8_t bf1) {
        f32x2_t zA = zero2, zB = zero2;
#pragma unroll
        for (int mt = 0; mt < 2; ++mt) {
            f32x4_t cA = b3q[mt], cB = b3q[mt];
            cA = __builtin_amdgcn_mfma_f32_16x16x32_f16(a3[mt * 2 + 0], af0, cA, 0, 0, 0);
            cB = __builtin_amdgcn_mfma_f32_16x16x32_f16(a3[mt * 2 + 0], bf0, cB, 0, 0, 0);
            cA = __builtin_amdgcn_mfma_f32_16x16x32_f16(a3[mt * 2 + 1], af1, cA, 0, 0, 0);
            cB = __builtin_amdgcn_mfma_f32_16x16x32_f16(a3[mt * 2 + 1], bf1, cB, 0, 0, 0);
            f32x2_t hA01 = __builtin_elementwise_max((f32x2_t){cA[0], cA[1]}, zero2);
            f32x2_t hB01 = __builtin_elementwise_max((f32x2_t){cB[0], cB[1]}, zero2);
            f32x2_t hA23 = __builtin_elementwise_max((f32x2_t){cA[2], cA[3]}, zero2);
            f32x2_t hB23 = __builtin_elementwise_max((f32x2_t){cB[2], cB[3]}, zero2);
            zA = __builtin_elementwise_fma(w4lo[mt], hA01, zA);
            zB = __builtin_elementwise_fma(w4lo[mt], hB01, zB);
            zA = __builtin_elementwise_fma(w4hi[mt], hA23, zA);
            zB = __builtin_elementwise_fma(w4hi[mt], hB23, zB);
        }
        zf[w * 512 + zi0 * 64 + l15 * 4 + quad] = zA[0] + zA[1];
        zf[w * 512 + zi1 * 64 + l15 * 4 + quad] = zB[0] + zB[1];
    };
    // phase C: batched reduce + sigmoid + coalesced store for an 8-group batch
    auto cphase = [&](int batch) {
#pragma unroll
        for (int half = 0; half < 2; ++half) {
            const int p = lane + 64 * half;   // point within this batch's 128
            const int pg = p >> 4, i = p & 15;
            float4 v = *(const float4*)&zf[w * 512 + pg * 64 + i * 4];
            float z = (v.x + v.y) + (v.z + v.w) + bias4;
            out[outbase + batch * 128 + p] = 1.0f / (1.0f + __expf(-z));
        }
    };

    // pipeline accumulators: Aa = even-index computes, Ab = odd-index
    Acc8 Aa, Ab;

    // ========== jrow-outer main loop: 8 jrows x 2 E/O body-pairs ==========
    // Wave w owns jrows [w*8, w*8+8). Pipeline index i = jr*4 + 2*pgp2 (+1).
    // compute@i, pack@i+1 (E packs Ab->slots 2,3 / O packs Aa->slots 0,1),
    // prefetch+bphase@i+2 (E reads 0,1 / O reads 2,3).
    for (int jr = 0; jr < 8; ++jr) {
        // base pairs for this jrow: 16 packed regs, pinned
        const unsigned* bp = &s_basep[w * 8 + jr][0];
#pragma unroll
        for (int kb = 0; kb < 4; ++kb) {
            uint4 v = *(const uint4*)&bp[kb * 16 + quad * 4];
            tbp[kb * 4 + 0] = v.x; tbp[kb * 4 + 1] = v.y;
            tbp[kb * 4 + 2] = v.z; tbp[kb * 4 + 3] = v.w;
        }
#pragma unroll
        for (int i = 0; i < 16; ++i) asm volatile("" : "+v"(tbp[i]));

#pragma unroll
        for (int pgp2 = 0; pgp2 < 2; ++pgp2) {
            const int iE = jr * 4 + 2 * pgp2;   // even pipeline index
            // ---------- half-body E: compute->Aa, bphase slots 0,1, pack<-Ab --
            {
                const bool doB = (iE >= 2);          // false only at jr=0,pgp2=0
                h16x8_t f0, f1, f2, f3;
                if (doB) prefetch2(0, 1, f0, f1, f2, f3);
                // deferred cphase for batch jr-1: zf written one half-body ago;
                // placed BEFORE bphase overwrites zf[0],zf[1].
                if (pgp2 == 1 && jr >= 1) cphase(jr - 1);
                aphase2(4 * pgp2, Aa);               // groups 2iE, 2iE+1 -> Aa
                if (doB) bphase2(pgp2 == 0 ? 4 : 0, pgp2 == 0 ? 5 : 1,
                                 f0, f1, f2, f3);    // groups 2iE-4, 2iE-3
                if (doB) packstore2(2, 3, Ab);       // groups 2iE-2, 2iE-1
            }
            // ---------- half-body O: compute->Ab, bphase slots 2,3, pack<-Aa --
            {
                const bool doB = (iE + 1 >= 2);      // false only at jr=0,pgp2=0
                h16x8_t f0, f1, f2, f3;
                if (doB) prefetch2(2, 3, f0, f1, f2, f3);
                aphase2(4 * pgp2 + 2, Ab);           // groups 2iE+2, 2iE+3 -> Ab
                if (doB) bphase2(pgp2 == 0 ? 6 : 2, pgp2 == 0 ? 7 : 3,
                                 f0, f1, f2, f3);    // groups 2iE-2, 2iE-1
                packstore2(0, 1, Aa);                // groups 2iE, 2iE+1
            }
        }
    }
    // ========== drain: i=32 (E-like) and i=33 (O-like) ==========
    {
        h16x8_t f0, f1, f2, f3;
        prefetch2(0, 1, f0, f1, f2, f3);
        bphase2(4, 5, f0, f1, f2, f3);       // groups 60, 61
        packstore2(2, 3, Ab);                // groups 62, 63
        prefetch2(2, 3, f0, f1, f2, f3);
        bphase2(6, 7, f0, f1, f2, f3);       // groups 62, 63
        cphase(7);
    }
}

extern "C" void kernel_launch(void* const* d_in, const int* in_sizes, int n_in,
                              void* d_out, int out_size, void* d_ws, size_t ws_size,
                              hipStream_t stream) {
    mlp_kernel<<<NPTS / 4096, 256, 0, stream>>>(
        (const float*)d_in[0], (const float*)d_in[1], (const float*)d_in[2],
        (const float*)d_in[3], (const float*)d_in[4], (const float*)d_in[5],
        (const float*)d_in[6], (const float*)d_in[7], (const float*)d_in[8],
        (float*)d_out);
}

// Round 9
// 110.449 us; speedup vs baseline: 1.7053x; 1.7053x over previous
//
#include <hip/hip_runtime.h>
#include <hip/hip_bf16.h>
#include <hip/hip_fp16.h>

// GeneratorSDF: latent-conditioned MLP SDF on a 128^3 grid (fp32 I/O).
// dims: 67 -> 128 -> 64 -> 32 -> 1 (relu, relu, relu, sigmoid)
//
// R31 = R28 verbatim (best verified: 50.0us) -- FINAL, declared practical
// structural ceiling per pre-committed criteria.
// Full ledger: R22 53.5 | R23 57.1 (permlane: added VALU costs 1:1) |
// R24 58.7 (reg pipeline) | R25 134 (3-wave attempt: spill; 2 waves/SIMD
// is a register-file hard floor, a2/a3=80 AGPR irreducible) | R26 54.1
// (setprio null) | R27 52.0 (dual-rail ILP +3%) | R28 50.0 (fused rails
// +4%) | R29 void (rule#20 scratch: lambda array-decay) | R30 137
// (depth-2 genuine capacity spill: needs ~184 arch VGPR, budget 176).
// Ceiling arithmetic: MFMA floor 20.7us (43 GFLOP @ 2.07 PF 16x16-f16
// ceiling); R28 = 2.4x floor at VALU 44 + MFMA 34 = 78% combined busy.
// Residual ~22% idle is per-wave dependency latency; hiding it needs more
// waves (blocked: R25) or more live pipeline state (blocked: R29/R30).
// Untried-but-large: 32x32x16 MFMA reshape (~20% MFMA-pipe savings, full
// fragment-layout rewrite). Everything cheap is exhausted.
// Structure: dual-rail fused (X/Y 16-pt groups, alternating MFMAs), grid
// 512 (4096 pts/block), jrow-outer 8x4-pairs, h2 4-slot LDS double-buffer
// + b3f prefetch, batched cphase, pinned twp/tbp, 4-way-parallel W1 fold,
// fp16 datapath, (256,2).
// MFMA layouts (verified m89/m91): A[m=lane&15][k=quad*8+j],
// B[k=quad*8+j][n=lane&15], C/D row=quad*4+reg, col=lane&15.

#define NPTS (128 * 128 * 128)

typedef float f32x4_t __attribute__((ext_vector_type(4)));
typedef float f32x2_t __attribute__((ext_vector_type(2)));
typedef __fp16 g16x2_t __attribute__((ext_vector_type(2)));    // VALU half2 (cvt_pkrtz type)
typedef _Float16 h16x8_t __attribute__((ext_vector_type(8)));  // MFMA fragment

__device__ __forceinline__ unsigned h2u(g16x2_t h) {
    unsigned u;
    __builtin_memcpy(&u, &h, 4);
    return u;
}
__device__ __forceinline__ g16x2_t u2h(unsigned u) {
    g16x2_t h;
    __builtin_memcpy(&h, &u, 4);
    return h;
}

__global__ __launch_bounds__(256, 2) void mlp_kernel(
    const float* __restrict__ x,  const float* __restrict__ W1,
    const float* __restrict__ b1, const float* __restrict__ W2,
    const float* __restrict__ b2, const float* __restrict__ W3,
    const float* __restrict__ b3, const float* __restrict__ W4,
    const float* __restrict__ b4, float* __restrict__ out) {
    __shared__ __align__(16) unsigned s_basep[32][64];  // half2 {base[2c],base[2c+1]} per j
    __shared__ __align__(16) unsigned s_wcp[64];        // half2 wc pairs
    __shared__ __align__(16) float s_b2[64];
    __shared__ __align__(16) float s_b3[32];
    __shared__ __align__(16) float s_w4[32];
    // Union (45 KB): staging = w2a[16][64][8] halves (0..8191) + w3a[4][64][8]
    // (8192..10239) + W1-fold partials (floats at shorts 10240..11263, transient);
    // runtime = h2 slots [w][4][16][72] shorts (0..18431) + zf floats
    // (shorts 18432..22527 = float[4][8][16][4] : w*512 + pg7*64 + i*4 + q).
    __shared__ __align__(16) unsigned short s_u[22528];

    const int t = threadIdx.x;
    const int w = t >> 6;
    const int lane = t & 63;
    const int quad = lane >> 4;
    const int l15 = lane & 15;
    const float step = 2.0f / 127.0f;

    // ================= per-block prep, phase 1 (all 256 threads) =============
    // W1 fold partials: thread covers channel-pair p = t&63, c in [h*16,(h+1)*16)
    {
        const int p = t & 63, h = t >> 6;
        const float* r0 = W1 + (2 * p) * 67 + h * 16;
        const float* r1 = r0 + 67;
        const float* xh = x + h * 16;
        float s0 = 0.0f, s1 = 0.0f;
#pragma unroll
        for (int c = 0; c < 16; ++c) {
            const float xc = xh[c];
            s0 = fmaf(r0[c], xc, s0);
            s1 = fmaf(r1[c], xc, s1);
        }
        float2* psum = (float2*)&s_u[10240];   // [h][p], 4 x 64 float2
        psum[h * 64 + p] = make_float2(s0, s1);
    }
    // W2 [64][128] -> f16 A-frag staging (pairs along k)
    const float2* W2v = (const float2*)W2;
#pragma unroll
    for (int it = 0; it < 16; ++it) {
        int pidx = t + 256 * it;
        int idx2 = pidx * 2;
        int o = idx2 >> 7, k = idx2 & 127;
        int mt = o >> 4, lm = o & 15;
        int kb = k >> 5, q = (k >> 3) & 3, jj = k & 7;
        float2 v = W2v[pidx];
        *(unsigned*)&s_u[(mt * 4 + kb) * 512 + (q * 16 + lm) * 8 + jj] =
            h2u(__builtin_amdgcn_cvt_pkrtz(v.x, v.y));
    }
    // W3 [32][64] -> f16 A-frag staging
    const float2* W3v = (const float2*)W3;
#pragma unroll
    for (int it = 0; it < 4; ++it) {
        int pidx = t + 256 * it;
        int idx2 = pidx * 2;
        int o = idx2 >> 6, k = idx2 & 63;
        int mt = o >> 4, lm = o & 15;
        int kb = k >> 5, q = (k >> 3) & 3, jj = k & 7;
        float2 v = W3v[pidx];
        *(unsigned*)&s_u[8192 + (mt * 2 + kb) * 512 + (q * 16 + lm) * 8 + jj] =
            h2u(__builtin_amdgcn_cvt_pkrtz(v.x, v.y));
    }
    if (t < 64) s_b2[t] = b2[t];
    if (t < 32) {
        s_b3[t] = b3[t];
        s_w4[t] = W4[t];
    }
    const float bias4 = b4[0];
    __syncthreads();

    // ================= prep phase 2 (t<64): combine partials + pack tables ====
    // Block covers gi = bid>>2 (a-coord), gj0 = (bid&3)*32 (32 j-rows), all k.
    if (t < 64) {
        const float2* psum = (const float2*)&s_u[10240];
        float2 q0 = psum[t], q1 = psum[64 + t], q2 = psum[128 + t], q3 = psum[192 + t];
        float s0 = b1[2 * t] + (q0.x + q1.x) + (q2.x + q3.x);
        float s1 = b1[2 * t + 1] + (q0.y + q1.y) + (q2.y + q3.y);
        const float* r0 = W1 + (2 * t) * 67;
        const float* r1 = r0 + 67;
        const float pa = -1.0f + step * (float)(blockIdx.x >> 2);   // gi
        const float base0 = fmaf(r0[64], pa, s0);
        const float base1 = fmaf(r1[64], pa, s1);
        const float wb0 = r0[65], wb1 = r1[65];
        const int gj0 = (blockIdx.x & 3) * 32;
        s_wcp[t] = h2u(__builtin_amdgcn_cvt_pkrtz(r0[66], r1[66]));
#pragma unroll
        for (int j = 0; j < 32; ++j) {
            const float pb = -1.0f + step * (float)(gj0 + j);
            s_basep[j][t] = h2u(__builtin_amdgcn_cvt_pkrtz(
                fmaf(wb0, pb, base0), fmaf(wb1, pb, base1)));
        }
    }
    __syncthreads();

    // ================= per-wave fragment preload =================
    h16x8_t a2[16];
#pragma unroll
    for (int f = 0; f < 16; ++f) a2[f] = *(const h16x8_t*)&s_u[f * 512 + lane * 8];
    h16x8_t a3[4];
#pragma unroll
    for (int f = 0; f < 4; ++f) a3[f] = *(const h16x8_t*)&s_u[8192 + f * 512 + lane * 8];
    f32x4_t b2q[4];
#pragma unroll
    for (int mt = 0; mt < 4; ++mt) b2q[mt] = *(const f32x4_t*)&s_b2[mt * 16 + quad * 4];
    f32x4_t b3q[2];
    f32x2_t w4lo[2], w4hi[2];
#pragma unroll
    for (int mt = 0; mt < 2; ++mt) {
        b3q[mt] = *(const f32x4_t*)&s_b3[mt * 16 + quad * 4];
        float4 wq = *(const float4*)&s_w4[mt * 16 + quad * 4];
        w4lo[mt][0] = wq.x; w4lo[mt][1] = wq.y;
        w4hi[mt][0] = wq.z; w4hi[mt][1] = wq.w;
    }
    // wc pairs: loop-invariant, 16 packed regs, pinned
    unsigned twp[16];
#pragma unroll
    for (int kb = 0; kb < 4; ++kb) {
        uint4 v = *(const uint4*)&s_wcp[kb * 16 + quad * 4];
        twp[kb * 4 + 0] = v.x; twp[kb * 4 + 1] = v.y;
        twp[kb * 4 + 2] = v.z; twp[kb * 4 + 3] = v.w;
    }
#pragma unroll
    for (int i = 0; i < 16; ++i) asm volatile("" : "+v"(twp[i]));
    __syncthreads();  // union handoff: staging -> h2/zf scratch

    const int sw = (l15 & 1) * 32;                    // h2 channel swizzle (shorts)
    unsigned short* h2w = &s_u[w * 4608];             // 4 slots x 16 pts x 72 shorts
    float* zf = (float*)&s_u[18432];                  // [w][pg&7][i][q]
    const f32x2_t zero2 = {0.0f, 0.0f};
    const g16x2_t zero2h = {(__fp16)0.0f, (__fp16)0.0f};
    const int outbase = blockIdx.x * 4096 + w * 1024;

    // ---- dual-rail phase bodies: rails fused instruction-by-instruction ----
    unsigned tbp[16];
    // A-phase x2: layer 1 + layer 2 for groups pgX, pgY (alternating MFMAs)
    auto aphase2 = [&](int pgX, int pgY, f32x4_t accX[4], f32x4_t accY[4]) {
        const float pcX = fmaf(step, (float)((pgX * 16) + l15), -1.0f);
        const float pcY = fmaf(step, (float)((pgY * 16) + l15), -1.0f);
        const g16x2_t pc2X = __builtin_amdgcn_cvt_pkrtz(pcX, pcX);
        const g16x2_t pc2Y = __builtin_amdgcn_cvt_pkrtz(pcY, pcY);
        h16x8_t bfX[4], bfY[4];
#pragma unroll
        for (int kb = 0; kb < 4; ++kb) {
            union { h16x8_t v; g16x2_t h[4]; } bx, by;
#pragma unroll
            for (int p = 0; p < 4; ++p) {
                g16x2_t tw = u2h(twp[kb * 4 + p]);
                g16x2_t tb = u2h(tbp[kb * 4 + p]);
                g16x2_t hx = __builtin_elementwise_fma(tw, pc2X, tb);
                g16x2_t hy = __builtin_elementwise_fma(tw, pc2Y, tb);
                bx.h[p] = __builtin_elementwise_max(hx, zero2h);
                by.h[p] = __builtin_elementwise_max(hy, zero2h);
            }
            bfX[kb] = bx.v;
            bfY[kb] = by.v;
        }
#pragma unroll
        for (int mt = 0; mt < 4; ++mt) {
            f32x4_t cX = b2q[mt], cY = b2q[mt];
#pragma unroll
            for (int kb = 0; kb < 4; ++kb) {
                cX = __builtin_amdgcn_mfma_f32_16x16x32_f16(a2[mt * 4 + kb], bfX[kb], cX, 0, 0, 0);
                cY = __builtin_amdgcn_mfma_f32_16x16x32_f16(a2[mt * 4 + kb], bfY[kb], cY, 0, 0, 0);
            }
            accX[mt] = cX;
            accY[mt] = cY;
        }
    };
    // A3 x2: pack + relu + h2-slot writes, rails alternating
    auto a3store2 = [&](int ngX, int ngY, const f32x4_t accX[4], const f32x4_t accY[4]) {
        unsigned short* slotX = h2w + (ngX & 3) * 1152 + l15 * 72;
        unsigned short* slotY = h2w + (ngY & 3) * 1152 + l15 * 72;
#pragma unroll
        for (int mt = 0; mt < 4; ++mt) {
            g16x2_t loX = __builtin_elementwise_max(
                __builtin_amdgcn_cvt_pkrtz(accX[mt][0], accX[mt][1]), zero2h);
            g16x2_t loY = __builtin_elementwise_max(
                __builtin_amdgcn_cvt_pkrtz(accY[mt][0], accY[mt][1]), zero2h);
            g16x2_t hiX = __builtin_elementwise_max(
                __builtin_amdgcn_cvt_pkrtz(accX[mt][2], accX[mt][3]), zero2h);
            g16x2_t hiY = __builtin_elementwise_max(
                __builtin_amdgcn_cvt_pkrtz(accY[mt][2], accY[mt][3]), zero2h);
            uint2 pkX, pkY;
            pkX.x = h2u(loX); pkX.y = h2u(hiX);
            pkY.x = h2u(loY); pkY.y = h2u(hiY);
            *(uint2*)&slotX[(mt * 16 + quad * 4) ^ sw] = pkX;
            *(uint2*)&slotY[(mt * 16 + quad * 4) ^ sw] = pkY;
        }
    };
    // B-phase x2: layer 3 + w4-dot for groups pgA, pgB (alternating MFMAs)
    auto bphase2 = [&](int pgA, h16x8_t af0, h16x8_t af1,
                       int pgB, h16x8_t bf0, h16x8_t bf1) {
        f32x2_t zA = zero2, zB = zero2;
#pragma unroll
        for (int mt = 0; mt < 2; ++mt) {
            f32x4_t cA = b3q[mt], cB = b3q[mt];
            cA = __builtin_amdgcn_mfma_f32_16x16x32_f16(a3[mt * 2 + 0], af0, cA, 0, 0, 0);
            cB = __builtin_amdgcn_mfma_f32_16x16x32_f16(a3[mt * 2 + 0], bf0, cB, 0, 0, 0);
            cA = __builtin_amdgcn_mfma_f32_16x16x32_f16(a3[mt * 2 + 1], af1, cA, 0, 0, 0);
            cB = __builtin_amdgcn_mfma_f32_16x16x32_f16(a3[mt * 2 + 1], bf1, cB, 0, 0, 0);
            f32x2_t hA01 = __builtin_elementwise_max((f32x2_t){cA[0], cA[1]}, zero2);
            f32x2_t hB01 = __builtin_elementwise_max((f32x2_t){cB[0], cB[1]}, zero2);
            f32x2_t hA23 = __builtin_elementwise_max((f32x2_t){cA[2], cA[3]}, zero2);
            f32x2_t hB23 = __builtin_elementwise_max((f32x2_t){cB[2], cB[3]}, zero2);
            zA = __builtin_elementwise_fma(w4lo[mt], hA01, zA);
            zB = __builtin_elementwise_fma(w4lo[mt], hB01, zB);
            zA = __builtin_elementwise_fma(w4hi[mt], hA23, zA);
            zB = __builtin_elementwise_fma(w4hi[mt], hB23, zB);
        }
        zf[w * 512 + (pgA & 7) * 64 + l15 * 4 + quad] = zA[0] + zA[1];
        zf[w * 512 + (pgB & 7) * 64 + l15 * 4 + quad] = zB[0] + zB[1];
    };
    // phase C: batched reduce + sigmoid + coalesced store for an 8-ng batch
    auto cphase = [&](int batch) {
#pragma unroll
        for (int half = 0; half < 2; ++half) {
            const int p = lane + 64 * half;   // point within this batch's 128
            const int pg = p >> 4, i = p & 15;
            float4 v = *(const float4*)&zf[w * 512 + pg * 64 + i * 4];
            float z = (v.x + v.y) + (v.z + v.w) + bias4;
            out[outbase + batch * 128 + p] = 1.0f / (1.0f + __expf(-z));
        }
    };

    // ========== jrow-outer main loop: 8 jrows x 4 pair-iterations ==========
    // Wave w owns jrows [w*8, w*8+8); group ng = jr*8 + pg, pg in [0,8).
    // Pair-iteration handles A(2i),A(2i+1) and B(2i-2),B(2i-1).
    for (int jr = 0; jr < 8; ++jr) {
        // base pairs for this jrow: 16 packed regs, pinned
        const unsigned* bp = &s_basep[w * 8 + jr][0];
#pragma unroll
        for (int kb = 0; kb < 4; ++kb) {
            uint4 v = *(const uint4*)&bp[kb * 16 + quad * 4];
            tbp[kb * 4 + 0] = v.x; tbp[kb * 4 + 1] = v.y;
            tbp[kb * 4 + 2] = v.z; tbp[kb * 4 + 3] = v.w;
        }
#pragma unroll
        for (int i = 0; i < 16; ++i) asm volatile("" : "+v"(tbp[i]));

#pragma unroll 2
        for (int pgp = 0; pgp < 4; ++pgp) {
            const int pgX = 2 * pgp, pgY = pgX + 1;
            const int ngX = jr * 8 + pgX, ngY = ngX + 1;
            // ---- prefetch b3f fragments for bphase(ngX-2), bphase(ngY-2) ----
            h16x8_t bxf0, bxf1, byf0, byf1;
            if (ngX > 1) {
                const unsigned short* ps0 = h2w + ((ngX - 2) & 3) * 1152 + l15 * 72;
                bxf0 = *(const h16x8_t*)&ps0[(0 ^ sw) + quad * 8];
                bxf1 = *(const h16x8_t*)&ps0[(32 ^ sw) + quad * 8];
                const unsigned short* ps1 = h2w + ((ngY - 2) & 3) * 1152 + l15 * 72;
                byf0 = *(const h16x8_t*)&ps1[(0 ^ sw) + quad * 8];
                byf1 = *(const h16x8_t*)&ps1[(32 ^ sw) + quad * 8];
            }
            // ---- fused dual-rail A-phase (alternating independent MFMAs) ----
            f32x4_t accX[4], accY[4];
            aphase2(pgX, pgY, accX, accY);
            a3store2(ngX, ngY, accX, accY);
            // ---- fused dual-rail B-phase for the previous pair ----
            if (ngX > 1) {
                bphase2(ngX - 2, bxf0, bxf1, ngY - 2, byf0, byf1);
                if (((ngY - 2) & 7) == 7) cphase((ngY - 2) >> 3);
            }
        }
    }
    {   // drain: groups 62, 63 + final batch
        const unsigned short* ps0 = h2w + (62 & 3) * 1152 + l15 * 72;
        h16x8_t bxf0 = *(const h16x8_t*)&ps0[(0 ^ sw) + quad * 8];
        h16x8_t bxf1 = *(const h16x8_t*)&ps0[(32 ^ sw) + quad * 8];
        const unsigned short* ps1 = h2w + (63 & 3) * 1152 + l15 * 72;
        h16x8_t byf0 = *(const h16x8_t*)&ps1[(0 ^ sw) + quad * 8];
        h16x8_t byf1 = *(const h16x8_t*)&ps1[(32 ^ sw) + quad * 8];
        bphase2(62, bxf0, bxf1, 63, byf0, byf1);
        cphase(7);
    }
}

extern "C" void kernel_launch(void* const* d_in, const int* in_sizes, int n_in,
                              void* d_out, int out_size, void* d_ws, size_t ws_size,
                              hipStream_t stream) {
    mlp_kernel<<<NPTS / 4096, 256, 0, stream>>>(
        (const float*)d_in[0], (const float*)d_in[1], (const float*)d_in[2],
        (const float*)d_in[3], (const float*)d_in[4], (const float*)d_in[5],
        (const float*)d_in[6], (const float*)d_in[7], (const float*)d_in[8],
        (float*)d_out);
}